// Round 1
// baseline (483.550 us; speedup 1.0000x reference)
//
#include <hip/hip_runtime.h>
#include <math.h>

#define BB 64
#define HH 480
#define WW 640
#define PH 64
#define PW 512
#define FS 15
#define NF 7
#define RR 7              // FS/2
#define GD 448            // B*NF
#define KTOT 32768        // PH*PW
#define KCH 2048          // K chunk per z-block (16 chunks)
#define KB 16             // K per LDS stage

static constexpr long CODES_N = (long)BB * NF * PH * PW;   // 14,680,064
static constexpr long GRAM_N  = (long)GD * GD;             // 200,704
static constexpr long POLAR_N = (long)BB * PH * PW;        // 2,097,152

// ---------------------------------------------------------------- K1: polar unwarp
__global__ __launch_bounds__(256) void polar_kernel(
        const float* __restrict__ img,
        const float* __restrict__ pupil,
        const float* __restrict__ iris,
        float* __restrict__ polar) {
    int t = blockIdx.x * 256 + threadIdx.x;
    if (t >= (int)POLAR_N) return;
    int j = t & (PW - 1);
    int i = (t >> 9) & (PH - 1);
    int b = t >> 15;

    // theta = 2*pi*(j+1)/PW, in fp32 matching the reference op order
    float theta = 6.2831855f * (float)(j + 1) / (float)PW;
    float s, c;
    sincosf(theta, &s, &c);

    float pcx = pupil[b * 3 + 0], pcy = pupil[b * 3 + 1], pr = pupil[b * 3 + 2];
    float icx = iris[b * 3 + 0],  icy = iris[b * 3 + 1],  ir = iris[b * 3 + 2];

    float px = pcx + pr * c;
    float py = pcy + pr * s;
    float ix = icx + ir * c;
    float iy = icy + ir * s;

    float r = (float)i / 63.0f;
    float xg = (1.0f - r) * px + r * ix;
    float yg = (1.0f - r) * py + r * iy;

    float x = fminf(fmaxf(xg, 0.0f), (float)(WW - 1));
    float y = fminf(fmaxf(yg, 0.0f), (float)(HH - 1));

    // Reference's normalize -> grid -> denormalize chain (NOT identity):
    float xn = x / (float)(WW - 1) * 2.0f - 1.0f;
    float gx = ((xn + 1.0f) / 2.0f * (float)WW - 0.5f) / (float)(WW - 1) * 2.0f - 1.0f;
    float xs = ((gx + 1.0f) * (float)WW - 1.0f) / 2.0f;

    float yn = y / (float)(HH - 1) * 2.0f - 1.0f;
    float gy = ((yn + 1.0f) / 2.0f * (float)HH - 0.5f) / (float)(HH - 1) * 2.0f - 1.0f;
    float ys = ((gy + 1.0f) * (float)HH - 1.0f) / 2.0f;

    float x0f = floorf(xs), y0f = floorf(ys);
    float wx = xs - x0f, wy = ys - y0f;
    int x0 = (int)x0f, y0 = (int)y0f;

    const float* im = img + (size_t)b * (HH * WW);
    float v00 = 0.f, v01 = 0.f, v10 = 0.f, v11 = 0.f;
    bool xv0 = (x0 >= 0) & (x0 < WW);
    bool xv1 = (x0 + 1 >= 0) & (x0 + 1 < WW);
    bool yv0 = (y0 >= 0) & (y0 < HH);
    bool yv1 = (y0 + 1 >= 0) & (y0 + 1 < HH);
    if (xv0 & yv0) v00 = im[(size_t)y0 * WW + x0];
    if (xv1 & yv0) v01 = im[(size_t)y0 * WW + x0 + 1];
    if (xv0 & yv1) v10 = im[(size_t)(y0 + 1) * WW + x0];
    if (xv1 & yv1) v11 = im[(size_t)(y0 + 1) * WW + x0 + 1];

    float val = v00 * (1.0f - wx) * (1.0f - wy) + v01 * wx * (1.0f - wy)
              + v10 * (1.0f - wx) * wy          + v11 * wx * wy;
    polar[t] = val * 255.0f;
}

// ---------------------------------------------------------------- K2: wrap conv 15x15x7
__global__ __launch_bounds__(128) void conv_kernel(
        const float* __restrict__ polar,
        const float* __restrict__ fm,
        float* __restrict__ codes) {
    __shared__ float sRow[FS][PW + FS + 1];   // 15 x 528 (526 used)
    __shared__ float sW[FS * FS][8];          // [tap][o], channel-flipped

    int b = blockIdx.x >> 6;
    int i = blockIdx.x & 63;
    int tid = threadIdx.x;

    const float* pb = polar + (size_t)b * (PH * PW);
    for (int u = 0; u < FS; ++u) {
        int ru = (i + u - RR + PH) & (PH - 1);
        const float* prow = pb + (size_t)ru * PW;
        for (int l = tid; l < PW + FS - 1; l += 128)
            sRow[u][l] = prow[(l + PW - RR) & (PW - 1)];
    }
    for (int tap = tid; tap < FS * FS; tap += 128) {
        #pragma unroll
        for (int o = 0; o < NF; ++o)
            sW[tap][o] = fm[tap * NF + (NF - 1 - o)];
    }
    __syncthreads();

    float acc[4][NF];
    #pragma unroll
    for (int jo = 0; jo < 4; ++jo)
        #pragma unroll
        for (int o = 0; o < NF; ++o) acc[jo][o] = 0.0f;

    int jb = tid * 4;
    for (int u = 0; u < FS; ++u) {
        float win[18];
        #pragma unroll
        for (int l = 0; l < 18; ++l) win[l] = sRow[u][jb + l];
        #pragma unroll
        for (int v = 0; v < FS; ++v) {
            float w[NF];
            #pragma unroll
            for (int o = 0; o < NF; ++o) w[o] = sW[u * FS + v][o];
            #pragma unroll
            for (int jo = 0; jo < 4; ++jo) {
                float val = win[jo + v];
                #pragma unroll
                for (int o = 0; o < NF; ++o)
                    acc[jo][o] = fmaf(val, w[o], acc[jo][o]);
            }
        }
    }

    #pragma unroll
    for (int o = 0; o < NF; ++o) {
        float4 v = make_float4(acc[0][o], acc[1][o], acc[2][o], acc[3][o]);
        *(float4*)&codes[(((size_t)b * NF + o) * PH + i) * PW + jb] = v;
    }
}

// ---------------------------------------------------------------- K3: gram (SYRK, split-K, atomics)
__global__ __launch_bounds__(256) void gram_kernel(
        const float* __restrict__ feats,
        float* __restrict__ gram) {
    int bx = blockIdx.x, by = blockIdx.y, bz = blockIdx.z;
    if (bx < by) return;   // symmetry: compute upper triangle of tiles only

    __shared__ float As[KB][68];
    __shared__ float Bs[KB][68];

    int tx = threadIdx.x & 15, ty = threadIdx.x >> 4;
    int p0 = by * 64, q0 = bx * 64;
    int lrow = threadIdx.x >> 2;        // 0..63
    int lk4 = (threadIdx.x & 3) * 4;    // 0,4,8,12

    float acc[4][4] = {{0.f}};

    int k_end = bz * KCH + KCH;
    for (int kb = bz * KCH; kb < k_end; kb += KB) {
        float4 av = *(const float4*)&feats[(size_t)(p0 + lrow) * KTOT + kb + lk4];
        float4 bv = *(const float4*)&feats[(size_t)(q0 + lrow) * KTOT + kb + lk4];
        __syncthreads();
        As[lk4 + 0][lrow] = av.x; As[lk4 + 1][lrow] = av.y;
        As[lk4 + 2][lrow] = av.z; As[lk4 + 3][lrow] = av.w;
        Bs[lk4 + 0][lrow] = bv.x; Bs[lk4 + 1][lrow] = bv.y;
        Bs[lk4 + 2][lrow] = bv.z; Bs[lk4 + 3][lrow] = bv.w;
        __syncthreads();
        #pragma unroll
        for (int kk = 0; kk < KB; ++kk) {
            float4 a = *(const float4*)&As[kk][4 * ty];
            float4 bq = *(const float4*)&Bs[kk][4 * tx];
            float ar[4] = {a.x, a.y, a.z, a.w};
            float br[4] = {bq.x, bq.y, bq.z, bq.w};
            #pragma unroll
            for (int ii = 0; ii < 4; ++ii)
                #pragma unroll
                for (int jj = 0; jj < 4; ++jj)
                    acc[ii][jj] = fmaf(ar[ii], br[jj], acc[ii][jj]);
        }
    }

    const float scale = 1.0f / 14680064.0f;
    #pragma unroll
    for (int ii = 0; ii < 4; ++ii) {
        int p = p0 + 4 * ty + ii;
        #pragma unroll
        for (int jj = 0; jj < 4; ++jj) {
            int q = q0 + 4 * tx + jj;
            float v = acc[ii][jj] * scale;
            atomicAdd(&gram[(size_t)p * GD + q], v);
            if (bx > by) atomicAdd(&gram[(size_t)q * GD + p], v);
        }
    }
}

// ---------------------------------------------------------------- launch
extern "C" void kernel_launch(void* const* d_in, const int* in_sizes, int n_in,
                              void* d_out, int out_size, void* d_ws, size_t ws_size,
                              hipStream_t stream) {
    const float* img   = (const float*)d_in[0];
    const float* pupil = (const float*)d_in[1];
    const float* iris  = (const float*)d_in[2];
    const float* fm    = (const float*)d_in[3];

    float* codes = (float*)d_out;
    float* gram  = codes + CODES_N;
    float* polar = gram + GRAM_N;

    // zero the gram region (atomic accumulation target)
    hipMemsetAsync(gram, 0, GRAM_N * sizeof(float), stream);

    polar_kernel<<<(int)(POLAR_N / 256), 256, 0, stream>>>(img, pupil, iris, polar);

    conv_kernel<<<BB * PH, 128, 0, stream>>>(polar, fm, codes);

    dim3 ggrid(7, 7, KTOT / KCH);
    gram_kernel<<<ggrid, 256, 0, stream>>>(codes, gram);
}

// Round 2
// 416.193 us; speedup vs baseline: 1.1618x; 1.1618x over previous
//
#include <hip/hip_runtime.h>
#include <math.h>

#define BB 64
#define HH 480
#define WW 640
#define PH 64
#define PW 512
#define FS 15
#define NF 7
#define RR 7              // FS/2
#define GD 448            // B*NF
#define KTOT 32768        // PH*PW

#define TS 64             // gram tile
#define SPLITS 32         // K splits
#define KPB (KTOT / SPLITS)   // 1024 K per block
#define KB2 16            // K per LDS stage

static constexpr long CODES_N = (long)BB * NF * PH * PW;   // 14,680,064
static constexpr long GRAM_N  = (long)GD * GD;             // 200,704
static constexpr long POLAR_N = (long)BB * PH * PW;        // 2,097,152

// upper-triangle 64x64 tile pairs (by<=bx), 7 tiles -> 28 pairs
__constant__ int c_by[28] = {0,0,0,0,0,0,0, 1,1,1,1,1,1, 2,2,2,2,2, 3,3,3,3, 4,4,4, 5,5, 6};
__constant__ int c_bx[28] = {0,1,2,3,4,5,6, 1,2,3,4,5,6, 2,3,4,5,6, 3,4,5,6, 4,5,6, 5,6, 6};

// ---------------------------------------------------------------- K1: polar unwarp
__global__ __launch_bounds__(256) void polar_kernel(
        const float* __restrict__ img,
        const float* __restrict__ pupil,
        const float* __restrict__ iris,
        float* __restrict__ polar) {
    int t = blockIdx.x * 256 + threadIdx.x;
    if (t >= (int)POLAR_N) return;
    int j = t & (PW - 1);
    int i = (t >> 9) & (PH - 1);
    int b = t >> 15;

    float theta = 6.2831855f * (float)(j + 1) / (float)PW;
    float s, c;
    __sincosf(theta, &s, &c);

    float pcx = pupil[b * 3 + 0], pcy = pupil[b * 3 + 1], pr = pupil[b * 3 + 2];
    float icx = iris[b * 3 + 0],  icy = iris[b * 3 + 1],  ir = iris[b * 3 + 2];

    float px = pcx + pr * c;
    float py = pcy + pr * s;
    float ix = icx + ir * c;
    float iy = icy + ir * s;

    float r = (float)i / 63.0f;
    float xg = (1.0f - r) * px + r * ix;
    float yg = (1.0f - r) * py + r * iy;

    float x = fminf(fmaxf(xg, 0.0f), (float)(WW - 1));
    float y = fminf(fmaxf(yg, 0.0f), (float)(HH - 1));

    float xn = x / (float)(WW - 1) * 2.0f - 1.0f;
    float gx = ((xn + 1.0f) / 2.0f * (float)WW - 0.5f) / (float)(WW - 1) * 2.0f - 1.0f;
    float xs = ((gx + 1.0f) * (float)WW - 1.0f) / 2.0f;

    float yn = y / (float)(HH - 1) * 2.0f - 1.0f;
    float gy = ((yn + 1.0f) / 2.0f * (float)HH - 0.5f) / (float)(HH - 1) * 2.0f - 1.0f;
    float ys = ((gy + 1.0f) * (float)HH - 1.0f) / 2.0f;

    float x0f = floorf(xs), y0f = floorf(ys);
    float wx = xs - x0f, wy = ys - y0f;
    int x0 = (int)x0f, y0 = (int)y0f;

    const float* im = img + (size_t)b * (HH * WW);
    float v00 = 0.f, v01 = 0.f, v10 = 0.f, v11 = 0.f;
    bool xv0 = (x0 >= 0) & (x0 < WW);
    bool xv1 = (x0 + 1 >= 0) & (x0 + 1 < WW);
    bool yv0 = (y0 >= 0) & (y0 < HH);
    bool yv1 = (y0 + 1 >= 0) & (y0 + 1 < HH);
    if (xv0 & yv0) v00 = im[(size_t)y0 * WW + x0];
    if (xv1 & yv0) v01 = im[(size_t)y0 * WW + x0 + 1];
    if (xv0 & yv1) v10 = im[(size_t)(y0 + 1) * WW + x0];
    if (xv1 & yv1) v11 = im[(size_t)(y0 + 1) * WW + x0 + 1];

    float val = v00 * (1.0f - wx) * (1.0f - wy) + v01 * wx * (1.0f - wy)
              + v10 * (1.0f - wx) * wy          + v11 * wx * wy;
    polar[t] = val * 255.0f;
}

// ---------------------------------------------------------------- K2: wrap conv 15x15x7
__global__ __launch_bounds__(128) void conv_kernel(
        const float* __restrict__ polar,
        const float* __restrict__ fm,
        float* __restrict__ codes) {
    __shared__ float sRow[FS][PW + FS + 1];   // 15 x 528 (526 used)
    __shared__ float sW[FS * FS][8];          // [tap][o], channel-flipped

    int b = blockIdx.x >> 6;
    int i = blockIdx.x & 63;
    int tid = threadIdx.x;

    const float* pb = polar + (size_t)b * (PH * PW);
    for (int u = 0; u < FS; ++u) {
        int ru = (i + u - RR + PH) & (PH - 1);
        const float* prow = pb + (size_t)ru * PW;
        float4 v = *(const float4*)&prow[tid * 4];
        *(float4*)&sRow[u][RR + tid * 4] = v;
        if (tid < RR) sRow[u][tid] = prow[505 + tid];              // left halo
        else if (tid < 2 * RR) sRow[u][512 + tid] = prow[tid - RR]; // right halo
    }
    for (int tap = tid; tap < FS * FS; tap += 128) {
        #pragma unroll
        for (int o = 0; o < NF; ++o)
            sW[tap][o] = fm[tap * NF + (NF - 1 - o)];
    }
    __syncthreads();

    float acc[4][NF];
    #pragma unroll
    for (int jo = 0; jo < 4; ++jo)
        #pragma unroll
        for (int o = 0; o < NF; ++o) acc[jo][o] = 0.0f;

    int jb = tid * 4;
    for (int u = 0; u < FS; ++u) {
        float win[18];
        #pragma unroll
        for (int l = 0; l < 18; ++l) win[l] = sRow[u][jb + l];
        #pragma unroll
        for (int v = 0; v < FS; ++v) {
            float w[NF];
            #pragma unroll
            for (int o = 0; o < NF; ++o) w[o] = sW[u * FS + v][o];
            #pragma unroll
            for (int jo = 0; jo < 4; ++jo) {
                float val = win[jo + v];
                #pragma unroll
                for (int o = 0; o < NF; ++o)
                    acc[jo][o] = fmaf(val, w[o], acc[jo][o]);
            }
        }
    }

    #pragma unroll
    for (int o = 0; o < NF; ++o) {
        float4 v = make_float4(acc[0][o], acc[1][o], acc[2][o], acc[3][o]);
        *(float4*)&codes[(((size_t)b * NF + o) * PH + i) * PW + jb] = v;
    }
}

// ---------------------------------------------------------------- K3: gram (SYRK, sym pairs, split-K, reg-prefetch pipeline)
__global__ __launch_bounds__(256) void gram_kernel(
        const float* __restrict__ feats,
        float* __restrict__ gram) {
    __shared__ float As[KB2][TS + 4];
    __shared__ float Bs[KB2][TS + 4];

    int pi = blockIdx.x;
    int by = c_by[pi], bx = c_bx[pi];
    int p0 = by * TS, q0 = bx * TS;

    int tid = threadIdx.x;
    int tx = tid & 15, ty = tid >> 4;
    int lrow = tid >> 2;              // 0..63
    int lk4 = (tid & 3) * 4;          // 0,4,8,12

    const float* aptr = feats + (size_t)(p0 + lrow) * KTOT + blockIdx.y * KPB + lk4;
    const float* bptr = feats + (size_t)(q0 + lrow) * KTOT + blockIdx.y * KPB + lk4;

    float4 an = *(const float4*)aptr;   // prefetch stage 0
    float4 bn = *(const float4*)bptr;

    float acc[4][4] = {{0.f}};

    constexpr int NSTAGE = KPB / KB2;   // 64
    for (int s = 0; s < NSTAGE; ++s) {
        __syncthreads();   // previous stage's LDS reads done
        As[lk4 + 0][lrow] = an.x; As[lk4 + 1][lrow] = an.y;
        As[lk4 + 2][lrow] = an.z; As[lk4 + 3][lrow] = an.w;
        Bs[lk4 + 0][lrow] = bn.x; Bs[lk4 + 1][lrow] = bn.y;
        Bs[lk4 + 2][lrow] = bn.z; Bs[lk4 + 3][lrow] = bn.w;
        __syncthreads();
        if (s + 1 < NSTAGE) {
            an = *(const float4*)(aptr + (size_t)(s + 1) * KB2);
            bn = *(const float4*)(bptr + (size_t)(s + 1) * KB2);
        }
        #pragma unroll
        for (int kk = 0; kk < KB2; ++kk) {
            float4 a = *(const float4*)&As[kk][4 * ty];
            float4 bq = *(const float4*)&Bs[kk][4 * tx];
            float ar[4] = {a.x, a.y, a.z, a.w};
            float br[4] = {bq.x, bq.y, bq.z, bq.w};
            #pragma unroll
            for (int ii = 0; ii < 4; ++ii)
                #pragma unroll
                for (int jj = 0; jj < 4; ++jj)
                    acc[ii][jj] = fmaf(ar[ii], br[jj], acc[ii][jj]);
        }
    }

    const float scale = 1.0f / 14680064.0f;
    #pragma unroll
    for (int ii = 0; ii < 4; ++ii) {
        int p = p0 + 4 * ty + ii;
        #pragma unroll
        for (int jj = 0; jj < 4; ++jj) {
            int q = q0 + 4 * tx + jj;
            float v = acc[ii][jj] * scale;
            atomicAdd(&gram[(size_t)p * GD + q], v);
            if (bx != by) atomicAdd(&gram[(size_t)q * GD + p], v);
        }
    }
}

// ---------------------------------------------------------------- launch
extern "C" void kernel_launch(void* const* d_in, const int* in_sizes, int n_in,
                              void* d_out, int out_size, void* d_ws, size_t ws_size,
                              hipStream_t stream) {
    const float* img   = (const float*)d_in[0];
    const float* pupil = (const float*)d_in[1];
    const float* iris  = (const float*)d_in[2];
    const float* fm    = (const float*)d_in[3];

    float* codes = (float*)d_out;
    float* gram  = codes + CODES_N;
    float* polar = gram + GRAM_N;

    hipMemsetAsync(gram, 0, GRAM_N * sizeof(float), stream);

    polar_kernel<<<(int)(POLAR_N / 256), 256, 0, stream>>>(img, pupil, iris, polar);

    conv_kernel<<<BB * PH, 128, 0, stream>>>(polar, fm, codes);

    dim3 ggrid(28, SPLITS);
    gram_kernel<<<ggrid, 256, 0, stream>>>(codes, gram);
}

// Round 3
// 410.040 us; speedup vs baseline: 1.1793x; 1.0150x over previous
//
#include <hip/hip_runtime.h>
#include <math.h>

#define BB 64
#define HH 480
#define WW 640
#define PH 64
#define PW 512
#define FS 15
#define NF 7
#define RR 7              // FS/2
#define GD 448            // B*NF
#define KTOT 32768        // PH*PW

#define SPLITS 32
#define KPB (KTOT / SPLITS)   // 1024 K per block
#define NSTEP (KPB / 16)      // 64 MFMA K-steps per block

static constexpr long CODES_N = (long)BB * NF * PH * PW;   // 14,680,064
static constexpr long GRAM_N  = (long)GD * GD;             // 200,704
static constexpr long POLAR_N = (long)BB * PH * PW;        // 2,097,152

typedef __bf16  bf16x8   __attribute__((ext_vector_type(8)));
typedef float   floatx16 __attribute__((ext_vector_type(16)));

// upper-triangle 64x64 tile pairs (by<=bx), 7 tiles -> 28 pairs
__constant__ int c_by[28] = {0,0,0,0,0,0,0, 1,1,1,1,1,1, 2,2,2,2,2, 3,3,3,3, 4,4,4, 5,5, 6};
__constant__ int c_bx[28] = {0,1,2,3,4,5,6, 1,2,3,4,5,6, 2,3,4,5,6, 3,4,5,6, 4,5,6, 5,6, 6};

// ---------------------------------------------------------------- K1: polar unwarp
__global__ __launch_bounds__(256) void polar_kernel(
        const float* __restrict__ img,
        const float* __restrict__ pupil,
        const float* __restrict__ iris,
        float* __restrict__ polar) {
    int t = blockIdx.x * 256 + threadIdx.x;
    if (t >= (int)POLAR_N) return;
    int j = t & (PW - 1);
    int i = (t >> 9) & (PH - 1);
    int b = t >> 15;

    float theta = 6.2831855f * (float)(j + 1) / (float)PW;
    float s, c;
    __sincosf(theta, &s, &c);

    float pcx = pupil[b * 3 + 0], pcy = pupil[b * 3 + 1], pr = pupil[b * 3 + 2];
    float icx = iris[b * 3 + 0],  icy = iris[b * 3 + 1],  ir = iris[b * 3 + 2];

    float px = pcx + pr * c;
    float py = pcy + pr * s;
    float ix = icx + ir * c;
    float iy = icy + ir * s;

    float r = (float)i / 63.0f;
    float xg = (1.0f - r) * px + r * ix;
    float yg = (1.0f - r) * py + r * iy;

    float x = fminf(fmaxf(xg, 0.0f), (float)(WW - 1));
    float y = fminf(fmaxf(yg, 0.0f), (float)(HH - 1));

    float xn = x / (float)(WW - 1) * 2.0f - 1.0f;
    float gx = ((xn + 1.0f) / 2.0f * (float)WW - 0.5f) / (float)(WW - 1) * 2.0f - 1.0f;
    float xs = ((gx + 1.0f) * (float)WW - 1.0f) / 2.0f;

    float yn = y / (float)(HH - 1) * 2.0f - 1.0f;
    float gy = ((yn + 1.0f) / 2.0f * (float)HH - 0.5f) / (float)(HH - 1) * 2.0f - 1.0f;
    float ys = ((gy + 1.0f) * (float)HH - 1.0f) / 2.0f;

    float x0f = floorf(xs), y0f = floorf(ys);
    float wx = xs - x0f, wy = ys - y0f;
    int x0 = (int)x0f, y0 = (int)y0f;

    const float* im = img + (size_t)b * (HH * WW);
    float v00 = 0.f, v01 = 0.f, v10 = 0.f, v11 = 0.f;
    bool xv0 = (x0 >= 0) & (x0 < WW);
    bool xv1 = (x0 + 1 >= 0) & (x0 + 1 < WW);
    bool yv0 = (y0 >= 0) & (y0 < HH);
    bool yv1 = (y0 + 1 >= 0) & (y0 + 1 < HH);
    if (xv0 & yv0) v00 = im[(size_t)y0 * WW + x0];
    if (xv1 & yv0) v01 = im[(size_t)y0 * WW + x0 + 1];
    if (xv0 & yv1) v10 = im[(size_t)(y0 + 1) * WW + x0];
    if (xv1 & yv1) v11 = im[(size_t)(y0 + 1) * WW + x0 + 1];

    float val = v00 * (1.0f - wx) * (1.0f - wy) + v01 * wx * (1.0f - wy)
              + v10 * (1.0f - wx) * wy          + v11 * wx * wy;
    polar[t] = val * 255.0f;
}

// ---------------------------------------------------------------- K2: wrap conv 15x15x7
__global__ __launch_bounds__(128) void conv_kernel(
        const float* __restrict__ polar,
        const float* __restrict__ fm,
        float* __restrict__ codes) {
    __shared__ float sRow[FS][PW + FS + 1];   // 15 x 528 (526 used)
    __shared__ float sW[FS * FS][8];          // [tap][o], channel-flipped

    int b = blockIdx.x >> 6;
    int i = blockIdx.x & 63;
    int tid = threadIdx.x;

    const float* pb = polar + (size_t)b * (PH * PW);
    for (int u = 0; u < FS; ++u) {
        int ru = (i + u - RR + PH) & (PH - 1);
        const float* prow = pb + (size_t)ru * PW;
        float4 v = *(const float4*)&prow[tid * 4];
        *(float4*)&sRow[u][RR + tid * 4] = v;
        if (tid < RR) sRow[u][tid] = prow[505 + tid];               // left halo
        else if (tid < 2 * RR) sRow[u][512 + tid] = prow[tid - RR]; // right halo
    }
    for (int tap = tid; tap < FS * FS; tap += 128) {
        #pragma unroll
        for (int o = 0; o < NF; ++o)
            sW[tap][o] = fm[tap * NF + (NF - 1 - o)];
    }
    __syncthreads();

    float acc[4][NF];
    #pragma unroll
    for (int jo = 0; jo < 4; ++jo)
        #pragma unroll
        for (int o = 0; o < NF; ++o) acc[jo][o] = 0.0f;

    int jb = tid * 4;
    for (int u = 0; u < FS; ++u) {
        float win[18];
        #pragma unroll
        for (int l = 0; l < 18; ++l) win[l] = sRow[u][jb + l];
        #pragma unroll
        for (int v = 0; v < FS; ++v) {
            float w[NF];
            #pragma unroll
            for (int o = 0; o < NF; ++o) w[o] = sW[u * FS + v][o];
            #pragma unroll
            for (int jo = 0; jo < 4; ++jo) {
                float val = win[jo + v];
                #pragma unroll
                for (int o = 0; o < NF; ++o)
                    acc[jo][o] = fmaf(val, w[o], acc[jo][o]);
            }
        }
    }

    #pragma unroll
    for (int o = 0; o < NF; ++o) {
        float4 v = make_float4(acc[0][o], acc[1][o], acc[2][o], acc[3][o]);
        *(float4*)&codes[(((size_t)b * NF + o) * PH + i) * PW + jb] = v;
    }
}

// ---------------------------------------------------------------- K3: gram via bf16 MFMA, hi/lo split
__device__ __forceinline__ void cvt_hilo(const float4& u, const float4& v,
                                         bf16x8& hi, bf16x8& lo) {
    float x[8] = {u.x, u.y, u.z, u.w, v.x, v.y, v.z, v.w};
    #pragma unroll
    for (int j = 0; j < 8; ++j) {
        __bf16 h = (__bf16)x[j];
        hi[j] = h;
        lo[j] = (__bf16)(x[j] - (float)h);
    }
}

__global__ __launch_bounds__(256) void gram_kernel(
        const float* __restrict__ feats,
        float* __restrict__ gram) {
    int pi = blockIdx.x;
    int by = c_by[pi], bx = c_bx[pi];
    int p0 = by * 64, q0 = bx * 64;

    int lane = threadIdx.x & 63;
    int w = threadIdx.x >> 6;        // wave 0..3
    int wr = w >> 1, wc = w & 1;     // 2x2 wave arrangement over the 64x64 tile
    int kq = (lane >> 5) * 8;        // 0 or 8: K sub-offset within the 16-K step

    int rowa = p0 + 32 * wr + (lane & 31);
    int rowb = q0 + 32 * wc + (lane & 31);
    const float* aptr = feats + (size_t)rowa * KTOT + (size_t)blockIdx.y * KPB + kq;
    const float* bptr = feats + (size_t)rowb * KTOT + (size_t)blockIdx.y * KPB + kq;

    floatx16 acc = {};

    // prefetch step 0
    float4 a0 = *(const float4*)aptr;
    float4 a1 = *(const float4*)(aptr + 4);
    float4 b0 = *(const float4*)bptr;
    float4 b1 = *(const float4*)(bptr + 4);

    #pragma unroll 4
    for (int s = 0; s < NSTEP; ++s) {
        float4 ca0 = a0, ca1 = a1, cb0 = b0, cb1 = b1;
        if (s + 1 < NSTEP) {
            const float* ap = aptr + (size_t)(s + 1) * 16;
            const float* bp = bptr + (size_t)(s + 1) * 16;
            a0 = *(const float4*)ap;
            a1 = *(const float4*)(ap + 4);
            b0 = *(const float4*)bp;
            b1 = *(const float4*)(bp + 4);
        }
        bf16x8 ah, al, bh, bl;
        cvt_hilo(ca0, ca1, ah, al);
        cvt_hilo(cb0, cb1, bh, bl);
        acc = __builtin_amdgcn_mfma_f32_32x32x16_bf16(ah, bh, acc, 0, 0, 0);
        acc = __builtin_amdgcn_mfma_f32_32x32x16_bf16(ah, bl, acc, 0, 0, 0);
        acc = __builtin_amdgcn_mfma_f32_32x32x16_bf16(al, bh, acc, 0, 0, 0);
    }

    const float scale = 1.0f / 14680064.0f;
    int col = lane & 31;
    #pragma unroll
    for (int r = 0; r < 16; ++r) {
        int row = (r & 3) + 8 * (r >> 2) + 4 * (lane >> 5);
        int p = p0 + 32 * wr + row;
        int q = q0 + 32 * wc + col;
        float v = acc[r] * scale;
        atomicAdd(&gram[(size_t)p * GD + q], v);
        if (bx != by) atomicAdd(&gram[(size_t)q * GD + p], v);
    }
}

// ---------------------------------------------------------------- launch
extern "C" void kernel_launch(void* const* d_in, const int* in_sizes, int n_in,
                              void* d_out, int out_size, void* d_ws, size_t ws_size,
                              hipStream_t stream) {
    const float* img   = (const float*)d_in[0];
    const float* pupil = (const float*)d_in[1];
    const float* iris  = (const float*)d_in[2];
    const float* fm    = (const float*)d_in[3];

    float* codes = (float*)d_out;
    float* gram  = codes + CODES_N;
    float* polar = gram + GRAM_N;

    hipMemsetAsync(gram, 0, GRAM_N * sizeof(float), stream);

    polar_kernel<<<(int)(POLAR_N / 256), 256, 0, stream>>>(img, pupil, iris, polar);

    conv_kernel<<<BB * PH, 128, 0, stream>>>(polar, fm, codes);

    dim3 ggrid(28, SPLITS);
    gram_kernel<<<ggrid, 256, 0, stream>>>(codes, gram);
}

// Round 4
// 356.474 us; speedup vs baseline: 1.3565x; 1.1503x over previous
//
#include <hip/hip_runtime.h>
#include <math.h>

#define BB 64
#define HH 480
#define WW 640
#define PH 64
#define PW 512
#define FS 15
#define NF 7
#define RR 7              // FS/2
#define GD 448            // B*NF
#define KTOT 32768        // PH*PW

#define SPLITS 32
#define KPB (KTOT / SPLITS)   // 1024 K per block
#define GBK 32                // K per LDS buffer
#define GNB (KPB / GBK)       // 32 buffers
#define PLW 40                // padded bf16 plane row width (16B-aligned rows, 4-way max)

#define SRW 536               // conv sRow padded width (16B-aligned rows)

static constexpr long CODES_N = (long)BB * NF * PH * PW;   // 14,680,064
static constexpr long GRAM_N  = (long)GD * GD;             // 200,704
static constexpr long POLAR_N = (long)BB * PH * PW;        // 2,097,152

typedef __bf16  bf16x4   __attribute__((ext_vector_type(4)));
typedef __bf16  bf16x8   __attribute__((ext_vector_type(8)));
typedef float   floatx16 __attribute__((ext_vector_type(16)));

// upper-triangle 64x64 tile pairs (by<=bx), 7 tiles -> 28 pairs
__constant__ int c_by[28] = {0,0,0,0,0,0,0, 1,1,1,1,1,1, 2,2,2,2,2, 3,3,3,3, 4,4,4, 5,5, 6};
__constant__ int c_bx[28] = {0,1,2,3,4,5,6, 1,2,3,4,5,6, 2,3,4,5,6, 3,4,5,6, 4,5,6, 5,6, 6};

// ---------------------------------------------------------------- K1: polar unwarp
__global__ __launch_bounds__(256) void polar_kernel(
        const float* __restrict__ img,
        const float* __restrict__ pupil,
        const float* __restrict__ iris,
        float* __restrict__ polar) {
    int t = blockIdx.x * 256 + threadIdx.x;
    if (t >= (int)POLAR_N) return;
    int j = t & (PW - 1);
    int i = (t >> 9) & (PH - 1);
    int b = t >> 15;

    float theta = 6.2831855f * (float)(j + 1) / (float)PW;
    float s, c;
    __sincosf(theta, &s, &c);

    float pcx = pupil[b * 3 + 0], pcy = pupil[b * 3 + 1], pr = pupil[b * 3 + 2];
    float icx = iris[b * 3 + 0],  icy = iris[b * 3 + 1],  ir = iris[b * 3 + 2];

    float px = pcx + pr * c;
    float py = pcy + pr * s;
    float ix = icx + ir * c;
    float iy = icy + ir * s;

    float r = (float)i / 63.0f;
    float xg = (1.0f - r) * px + r * ix;
    float yg = (1.0f - r) * py + r * iy;

    float x = fminf(fmaxf(xg, 0.0f), (float)(WW - 1));
    float y = fminf(fmaxf(yg, 0.0f), (float)(HH - 1));

    float xn = x / (float)(WW - 1) * 2.0f - 1.0f;
    float gx = ((xn + 1.0f) / 2.0f * (float)WW - 0.5f) / (float)(WW - 1) * 2.0f - 1.0f;
    float xs = ((gx + 1.0f) * (float)WW - 1.0f) / 2.0f;

    float yn = y / (float)(HH - 1) * 2.0f - 1.0f;
    float gy = ((yn + 1.0f) / 2.0f * (float)HH - 0.5f) / (float)(HH - 1) * 2.0f - 1.0f;
    float ys = ((gy + 1.0f) * (float)HH - 1.0f) / 2.0f;

    float x0f = floorf(xs), y0f = floorf(ys);
    float wx = xs - x0f, wy = ys - y0f;
    int x0 = (int)x0f, y0 = (int)y0f;

    const float* im = img + (size_t)b * (HH * WW);
    float v00 = 0.f, v01 = 0.f, v10 = 0.f, v11 = 0.f;
    bool xv0 = (x0 >= 0) & (x0 < WW);
    bool xv1 = (x0 + 1 >= 0) & (x0 + 1 < WW);
    bool yv0 = (y0 >= 0) & (y0 < HH);
    bool yv1 = (y0 + 1 >= 0) & (y0 + 1 < HH);
    if (xv0 & yv0) v00 = im[(size_t)y0 * WW + x0];
    if (xv1 & yv0) v01 = im[(size_t)y0 * WW + x0 + 1];
    if (xv0 & yv1) v10 = im[(size_t)(y0 + 1) * WW + x0];
    if (xv1 & yv1) v11 = im[(size_t)(y0 + 1) * WW + x0 + 1];

    float val = v00 * (1.0f - wx) * (1.0f - wy) + v01 * wx * (1.0f - wy)
              + v10 * (1.0f - wx) * wy          + v11 * wx * wy;
    polar[t] = val * 255.0f;
}

// ---------------------------------------------------------------- K2: wrap conv 15x15x7
// block = (b, 4 output rows); 4 waves, wave w -> row i0+w; thread: 8 j x 7 o.
__global__ __launch_bounds__(256) void conv_kernel(
        const float* __restrict__ polar,
        const float* __restrict__ fm,
        float* __restrict__ codes) {
    __shared__ float sRow[18][SRW];        // rows i0-7 .. i0+10, wrap-padded cols
    __shared__ float sW[FS * FS][8];       // [tap][o], channel-flipped

    int b  = blockIdx.x >> 4;
    int i0 = (blockIdx.x & 15) * 4;
    int tid = threadIdx.x;

    const float* pb = polar + (size_t)b * (PH * PW);

    // interior: 2 rows per pass, 128 threads/row, float4 each
    #pragma unroll
    for (int pass = 0; pass < 9; ++pass) {
        int r = pass * 2 + (tid >> 7);
        int c = tid & 127;
        int row = (i0 + r - RR) & (PH - 1);
        float4 v = *(const float4*)&pb[(size_t)row * PW + c * 4];
        *(float4*)&sRow[r][RR + c * 4] = v;
    }
    // halos: 18 rows x 14 cols = 252 scalars
    if (tid < 252) {
        int r = tid / 14, l = tid % 14;
        int row = (i0 + r - RR) & (PH - 1);
        const float* prow = pb + (size_t)row * PW;
        if (l < RR) sRow[r][l] = prow[505 + l];
        else        sRow[r][512 + l] = prow[l - RR];
    }
    if (tid < FS * FS) {
        #pragma unroll
        for (int o = 0; o < NF; ++o)
            sW[tid][o] = fm[tid * NF + (NF - 1 - o)];
    }
    __syncthreads();

    int w = tid >> 6;          // wave -> output row
    int lane = tid & 63;
    int jb = lane * 8;
    int i = i0 + w;

    float acc[8][NF];
    #pragma unroll
    for (int jo = 0; jo < 8; ++jo)
        #pragma unroll
        for (int o = 0; o < NF; ++o) acc[jo][o] = 0.0f;

    for (int u = 0; u < FS; ++u) {
        float win[22];
        #pragma unroll
        for (int l = 0; l < 22; ++l) win[l] = sRow[w + u][jb + l];
        #pragma unroll
        for (int v = 0; v < FS; ++v) {
            float wv[NF];
            #pragma unroll
            for (int o = 0; o < NF; ++o) wv[o] = sW[u * FS + v][o];
            #pragma unroll
            for (int jo = 0; jo < 8; ++jo) {
                float x = win[jo + v];
                #pragma unroll
                for (int o = 0; o < NF; ++o)
                    acc[jo][o] = fmaf(x, wv[o], acc[jo][o]);
            }
        }
    }

    #pragma unroll
    for (int o = 0; o < NF; ++o) {
        size_t base = (((size_t)b * NF + o) * PH + i) * PW + jb;
        *(float4*)&codes[base]     = make_float4(acc[0][o], acc[1][o], acc[2][o], acc[3][o]);
        *(float4*)&codes[base + 4] = make_float4(acc[4][o], acc[5][o], acc[6][o], acc[7][o]);
    }
}

// ---------------------------------------------------------------- K3: gram via bf16 MFMA, LDS-staged hi/lo planes
__device__ __forceinline__ void split4(float4 v, bf16x4& h, bf16x4& l) {
    float x[4] = {v.x, v.y, v.z, v.w};
    #pragma unroll
    for (int j = 0; j < 4; ++j) {
        __bf16 hh = (__bf16)x[j];
        h[j] = hh;
        l[j] = (__bf16)(x[j] - (float)hh);
    }
}

__global__ __launch_bounds__(256) void gram_kernel(
        const float* __restrict__ feats,
        float* __restrict__ gram) {
    __shared__ __bf16 Ah[2][64][PLW], Al[2][64][PLW];
    __shared__ __bf16 Bh[2][64][PLW], Bl[2][64][PLW];

    int pi = blockIdx.x;
    int by = c_by[pi], bx = c_bx[pi];
    int p0 = by * 64, q0 = bx * 64;
    int kbase = blockIdx.y * KPB;

    int tid = threadIdx.x;
    int lane = tid & 63;
    int w = tid >> 6;
    int wr = w >> 1, wc = w & 1;        // 2x2 waves over 64x64 tile

    // staging: 8 threads/row (float4 slots), rows r0 and r0+32
    int r0 = tid >> 3;                  // 0..31
    int slot = tid & 7;                 // k = slot*4
    const float* ap0 = feats + (size_t)(p0 + r0)      * KTOT + kbase + slot * 4;
    const float* ap1 = feats + (size_t)(p0 + r0 + 32) * KTOT + kbase + slot * 4;
    const float* bp0 = feats + (size_t)(q0 + r0)      * KTOT + kbase + slot * 4;
    const float* bp1 = feats + (size_t)(q0 + r0 + 32) * KTOT + kbase + slot * 4;

    // compute-side fragment indices
    int frow = lane & 31;
    int arow = 32 * wr + frow;
    int brow = 32 * wc + frow;
    int kq = (lane >> 5) * 8;

    floatx16 acc = {};

    // prologue: stage buffer 0
    {
        float4 a0 = *(const float4*)ap0;
        float4 a1 = *(const float4*)ap1;
        float4 b0 = *(const float4*)bp0;
        float4 b1 = *(const float4*)bp1;
        bf16x4 h, l;
        split4(a0, h, l); *(bf16x4*)&Ah[0][r0][slot*4] = h;      *(bf16x4*)&Al[0][r0][slot*4] = l;
        split4(a1, h, l); *(bf16x4*)&Ah[0][r0+32][slot*4] = h;   *(bf16x4*)&Al[0][r0+32][slot*4] = l;
        split4(b0, h, l); *(bf16x4*)&Bh[0][r0][slot*4] = h;      *(bf16x4*)&Bl[0][r0][slot*4] = l;
        split4(b1, h, l); *(bf16x4*)&Bh[0][r0+32][slot*4] = h;   *(bf16x4*)&Bl[0][r0+32][slot*4] = l;
    }
    __syncthreads();

    for (int s = 0; s < GNB; ++s) {
        int buf = s & 1;
        float4 a0, a1, b0, b1;
        if (s + 1 < GNB) {
            int off = (s + 1) * GBK;
            a0 = *(const float4*)(ap0 + off);
            a1 = *(const float4*)(ap1 + off);
            b0 = *(const float4*)(bp0 + off);
            b1 = *(const float4*)(bp1 + off);
        }
        #pragma unroll
        for (int kk = 0; kk < 2; ++kk) {
            int ko = kq + kk * 16;
            bf16x8 ah = *(const bf16x8*)&Ah[buf][arow][ko];
            bf16x8 al = *(const bf16x8*)&Al[buf][arow][ko];
            bf16x8 bh = *(const bf16x8*)&Bh[buf][brow][ko];
            bf16x8 bl = *(const bf16x8*)&Bl[buf][brow][ko];
            acc = __builtin_amdgcn_mfma_f32_32x32x16_bf16(ah, bh, acc, 0, 0, 0);
            acc = __builtin_amdgcn_mfma_f32_32x32x16_bf16(ah, bl, acc, 0, 0, 0);
            acc = __builtin_amdgcn_mfma_f32_32x32x16_bf16(al, bh, acc, 0, 0, 0);
        }
        if (s + 1 < GNB) {
            int nb = (s + 1) & 1;
            bf16x4 h, l;
            split4(a0, h, l); *(bf16x4*)&Ah[nb][r0][slot*4] = h;      *(bf16x4*)&Al[nb][r0][slot*4] = l;
            split4(a1, h, l); *(bf16x4*)&Ah[nb][r0+32][slot*4] = h;   *(bf16x4*)&Al[nb][r0+32][slot*4] = l;
            split4(b0, h, l); *(bf16x4*)&Bh[nb][r0][slot*4] = h;      *(bf16x4*)&Bl[nb][r0][slot*4] = l;
            split4(b1, h, l); *(bf16x4*)&Bh[nb][r0+32][slot*4] = h;   *(bf16x4*)&Bl[nb][r0+32][slot*4] = l;
        }
        __syncthreads();
    }

    const float scale = 1.0f / 14680064.0f;
    int col = lane & 31;
    #pragma unroll
    for (int r = 0; r < 16; ++r) {
        int row = (r & 3) + 8 * (r >> 2) + 4 * (lane >> 5);
        int p = p0 + 32 * wr + row;
        int q = q0 + 32 * wc + col;
        float v = acc[r] * scale;
        atomicAdd(&gram[(size_t)p * GD + q], v);
        if (bx != by) atomicAdd(&gram[(size_t)q * GD + p], v);
    }
}

// ---------------------------------------------------------------- launch
extern "C" void kernel_launch(void* const* d_in, const int* in_sizes, int n_in,
                              void* d_out, int out_size, void* d_ws, size_t ws_size,
                              hipStream_t stream) {
    const float* img   = (const float*)d_in[0];
    const float* pupil = (const float*)d_in[1];
    const float* iris  = (const float*)d_in[2];
    const float* fm    = (const float*)d_in[3];

    float* codes = (float*)d_out;
    float* gram  = codes + CODES_N;
    float* polar = gram + GRAM_N;

    hipMemsetAsync(gram, 0, GRAM_N * sizeof(float), stream);

    polar_kernel<<<(int)(POLAR_N / 256), 256, 0, stream>>>(img, pupil, iris, polar);

    conv_kernel<<<BB * (PH / 4), 256, 0, stream>>>(polar, fm, codes);

    dim3 ggrid(28, SPLITS);
    gram_kernel<<<ggrid, 256, 0, stream>>>(codes, gram);
}

// Round 5
// 329.998 us; speedup vs baseline: 1.4653x; 1.0802x over previous
//
#include <hip/hip_runtime.h>
#include <math.h>

#define BB 64
#define HH 480
#define WW 640
#define PH 64
#define PW 512
#define FS 15
#define NF 7
#define RR 7              // FS/2
#define GD 448            // B*NF
#define KTOT 32768        // PH*PW

#define SPLITS 32
#define KPB (KTOT / SPLITS)   // 1024 K per block
#define GSTK 64               // K per LDS stage (bf16 gram)
#define GNST (KPB / GSTK)     // 16 stages
#define GPLW 72               // padded LDS row width in bf16 elems (144 B)

// fallback (hi/lo) gram params
#define GBK 32
#define GNB (KPB / GBK)
#define PLW 40

#define SRW 536               // conv sRow padded width

static constexpr long CODES_N = (long)BB * NF * PH * PW;   // 14,680,064
static constexpr long GRAM_N  = (long)GD * GD;             // 200,704
static constexpr long POLAR_N = (long)BB * PH * PW;        // 2,097,152
static constexpr size_t BF_BYTES = (size_t)GD * KTOT * 2;  // 28 MB

typedef __bf16  bf16x4   __attribute__((ext_vector_type(4)));
typedef __bf16  bf16x8   __attribute__((ext_vector_type(8)));
typedef float   floatx16 __attribute__((ext_vector_type(16)));

// upper-triangle 64x64 tile pairs (by<=bx), 7 tiles -> 28 pairs
__constant__ int c_by[28] = {0,0,0,0,0,0,0, 1,1,1,1,1,1, 2,2,2,2,2, 3,3,3,3, 4,4,4, 5,5, 6};
__constant__ int c_bx[28] = {0,1,2,3,4,5,6, 1,2,3,4,5,6, 2,3,4,5,6, 3,4,5,6, 4,5,6, 5,6, 6};

// ---------------------------------------------------------------- K1: polar unwarp
__global__ __launch_bounds__(256) void polar_kernel(
        const float* __restrict__ img,
        const float* __restrict__ pupil,
        const float* __restrict__ iris,
        float* __restrict__ polar) {
    int t = blockIdx.x * 256 + threadIdx.x;
    if (t >= (int)POLAR_N) return;
    int j = t & (PW - 1);
    int i = (t >> 9) & (PH - 1);
    int b = t >> 15;

    float theta = 6.2831855f * (float)(j + 1) / (float)PW;
    float s, c;
    __sincosf(theta, &s, &c);

    float pcx = pupil[b * 3 + 0], pcy = pupil[b * 3 + 1], pr = pupil[b * 3 + 2];
    float icx = iris[b * 3 + 0],  icy = iris[b * 3 + 1],  ir = iris[b * 3 + 2];

    float px = pcx + pr * c;
    float py = pcy + pr * s;
    float ix = icx + ir * c;
    float iy = icy + ir * s;

    float r = (float)i / 63.0f;
    float xg = (1.0f - r) * px + r * ix;
    float yg = (1.0f - r) * py + r * iy;

    float x = fminf(fmaxf(xg, 0.0f), (float)(WW - 1));
    float y = fminf(fmaxf(yg, 0.0f), (float)(HH - 1));

    float xn = x / (float)(WW - 1) * 2.0f - 1.0f;
    float gx = ((xn + 1.0f) / 2.0f * (float)WW - 0.5f) / (float)(WW - 1) * 2.0f - 1.0f;
    float xs = ((gx + 1.0f) * (float)WW - 1.0f) / 2.0f;

    float yn = y / (float)(HH - 1) * 2.0f - 1.0f;
    float gy = ((yn + 1.0f) / 2.0f * (float)HH - 0.5f) / (float)(HH - 1) * 2.0f - 1.0f;
    float ys = ((gy + 1.0f) * (float)HH - 1.0f) / 2.0f;

    float x0f = floorf(xs), y0f = floorf(ys);
    float wx = xs - x0f, wy = ys - y0f;
    int x0 = (int)x0f, y0 = (int)y0f;

    const float* im = img + (size_t)b * (HH * WW);
    float v00 = 0.f, v01 = 0.f, v10 = 0.f, v11 = 0.f;
    bool xv0 = (x0 >= 0) & (x0 < WW);
    bool xv1 = (x0 + 1 >= 0) & (x0 + 1 < WW);
    bool yv0 = (y0 >= 0) & (y0 < HH);
    bool yv1 = (y0 + 1 >= 0) & (y0 + 1 < HH);
    if (xv0 & yv0) v00 = im[(size_t)y0 * WW + x0];
    if (xv1 & yv0) v01 = im[(size_t)y0 * WW + x0 + 1];
    if (xv0 & yv1) v10 = im[(size_t)(y0 + 1) * WW + x0];
    if (xv1 & yv1) v11 = im[(size_t)(y0 + 1) * WW + x0 + 1];

    float val = v00 * (1.0f - wx) * (1.0f - wy) + v01 * wx * (1.0f - wy)
              + v10 * (1.0f - wx) * wy          + v11 * wx * wy;
    polar[t] = val * 255.0f;
}

// ---------------------------------------------------------------- K2: wrap conv 15x15x7
// block = (b, 4 output rows); 4 waves, wave w -> row i0+w; thread: 8 j x 7 o.
// Optionally writes a bf16 copy of codes (row-major [448][32768]) to cbf.
__global__ __launch_bounds__(256) void conv_kernel(
        const float* __restrict__ polar,
        const float* __restrict__ fm,
        float* __restrict__ codes,
        __bf16* __restrict__ cbf) {
    __shared__ float sRow[18][SRW];        // rows i0-7 .. i0+10, wrap-padded cols
    __shared__ float sW[FS * FS][8];       // [tap][o], channel-flipped

    int b  = blockIdx.x >> 4;
    int i0 = (blockIdx.x & 15) * 4;
    int tid = threadIdx.x;

    const float* pb = polar + (size_t)b * (PH * PW);

    #pragma unroll
    for (int pass = 0; pass < 9; ++pass) {
        int r = pass * 2 + (tid >> 7);
        int c = tid & 127;
        int row = (i0 + r - RR) & (PH - 1);
        float4 v = *(const float4*)&pb[(size_t)row * PW + c * 4];
        *(float4*)&sRow[r][RR + c * 4] = v;
    }
    if (tid < 252) {
        int r = tid / 14, l = tid % 14;
        int row = (i0 + r - RR) & (PH - 1);
        const float* prow = pb + (size_t)row * PW;
        if (l < RR) sRow[r][l] = prow[505 + l];
        else        sRow[r][512 + l] = prow[l - RR];
    }
    if (tid < FS * FS) {
        #pragma unroll
        for (int o = 0; o < NF; ++o)
            sW[tid][o] = fm[tid * NF + (NF - 1 - o)];
    }
    __syncthreads();

    int w = tid >> 6;
    int lane = tid & 63;
    int jb = lane * 8;
    int i = i0 + w;

    float acc[8][NF];
    #pragma unroll
    for (int jo = 0; jo < 8; ++jo)
        #pragma unroll
        for (int o = 0; o < NF; ++o) acc[jo][o] = 0.0f;

    for (int u = 0; u < FS; ++u) {
        float win[22];
        #pragma unroll
        for (int l = 0; l < 22; ++l) win[l] = sRow[w + u][jb + l];
        #pragma unroll
        for (int v = 0; v < FS; ++v) {
            float wv[NF];
            #pragma unroll
            for (int o = 0; o < NF; ++o) wv[o] = sW[u * FS + v][o];
            #pragma unroll
            for (int jo = 0; jo < 8; ++jo) {
                float x = win[jo + v];
                #pragma unroll
                for (int o = 0; o < NF; ++o)
                    acc[jo][o] = fmaf(x, wv[o], acc[jo][o]);
            }
        }
    }

    #pragma unroll
    for (int o = 0; o < NF; ++o) {
        size_t base = (((size_t)b * NF + o) * PH + i) * PW + jb;
        *(float4*)&codes[base]     = make_float4(acc[0][o], acc[1][o], acc[2][o], acc[3][o]);
        *(float4*)&codes[base + 4] = make_float4(acc[4][o], acc[5][o], acc[6][o], acc[7][o]);
    }
    if (cbf) {
        #pragma unroll
        for (int o = 0; o < NF; ++o) {
            bf16x8 bv;
            #pragma unroll
            for (int jo = 0; jo < 8; ++jo) bv[jo] = (__bf16)acc[jo][o];
            // row = b*NF+o, col = i*PW + jb  (same flat index as codes)
            *(bf16x8*)&cbf[(((size_t)b * NF + o) * PH + i) * PW + jb] = bv;
        }
    }
}

// ---------------------------------------------------------------- K3: gram, pure bf16 MFMA SYRK
// 28 tile pairs x 32 K-splits; dbuf LDS K=64 stages; 2-stage register prefetch.
__global__ __launch_bounds__(256) void gram_bf_kernel(
        const __bf16* __restrict__ feats,
        float* __restrict__ gram) {
    __shared__ __bf16 Ab[2][64][GPLW];
    __shared__ __bf16 Bb[2][64][GPLW];

    int pi = blockIdx.x;
    int by = c_by[pi], bx = c_bx[pi];
    int p0 = by * 64, q0 = bx * 64;
    size_t kbase = (size_t)blockIdx.y * KPB;

    int tid = threadIdx.x;
    int lane = tid & 63;
    int w = tid >> 6;
    int wr = w >> 1, wc = w & 1;        // 2x2 waves over 64x64 tile

    // staging: thread covers rows (srow, srow+32), k-octet slot
    int srow = tid >> 3;                // 0..31
    int slot = tid & 7;                 // octet -> k = slot*8
    const __bf16* apA  = feats + (size_t)(p0 + srow) * KTOT + kbase + slot * 8;
    const __bf16* apA2 = apA + (size_t)32 * KTOT;
    const __bf16* apB  = feats + (size_t)(q0 + srow) * KTOT + kbase + slot * 8;
    const __bf16* apB2 = apB + (size_t)32 * KTOT;

    // compute-side fragment indices
    int arow = 32 * wr + (lane & 31);
    int brow = 32 * wc + (lane & 31);
    int ko = (lane >> 5) * 8;           // 0 or 8

    floatx16 acc = {};

    bf16x8 ra0 = *(const bf16x8*)(apA);
    bf16x8 ra1 = *(const bf16x8*)(apA2);
    bf16x8 rb0 = *(const bf16x8*)(apB);
    bf16x8 rb1 = *(const bf16x8*)(apB2);
    bf16x8 na0 = *(const bf16x8*)(apA + GSTK);
    bf16x8 na1 = *(const bf16x8*)(apA2 + GSTK);
    bf16x8 nb0 = *(const bf16x8*)(apB + GSTK);
    bf16x8 nb1 = *(const bf16x8*)(apB2 + GSTK);

    for (int s = 0; s < GNST; ++s) {
        int p = s & 1;
        *(bf16x8*)&Ab[p][srow][slot * 8]      = ra0;
        *(bf16x8*)&Ab[p][srow + 32][slot * 8] = ra1;
        *(bf16x8*)&Bb[p][srow][slot * 8]      = rb0;
        *(bf16x8*)&Bb[p][srow + 32][slot * 8] = rb1;
        __syncthreads();
        ra0 = na0; ra1 = na1; rb0 = nb0; rb1 = nb1;
        if (s + 2 < GNST) {
            size_t off = (size_t)(s + 2) * GSTK;
            na0 = *(const bf16x8*)(apA + off);
            na1 = *(const bf16x8*)(apA2 + off);
            nb0 = *(const bf16x8*)(apB + off);
            nb1 = *(const bf16x8*)(apB2 + off);
        }
        #pragma unroll
        for (int st = 0; st < 4; ++st) {
            bf16x8 af = *(const bf16x8*)&Ab[p][arow][st * 16 + ko];
            bf16x8 bg = *(const bf16x8*)&Bb[p][brow][st * 16 + ko];
            acc = __builtin_amdgcn_mfma_f32_32x32x16_bf16(af, bg, acc, 0, 0, 0);
        }
    }

    const float scale = 1.0f / 14680064.0f;
    int col = lane & 31;
    #pragma unroll
    for (int r = 0; r < 16; ++r) {
        int row = (r & 3) + 8 * (r >> 2) + 4 * (lane >> 5);
        int p = p0 + 32 * wr + row;
        int q = q0 + 32 * wc + col;
        float v = acc[r] * scale;
        atomicAdd(&gram[(size_t)p * GD + q], v);
        if (bx != by) atomicAdd(&gram[(size_t)q * GD + p], v);
    }
}

// ---------------------------------------------------------------- K3 fallback: hi/lo split (no ws needed)
__device__ __forceinline__ void split4(float4 v, bf16x4& h, bf16x4& l) {
    float x[4] = {v.x, v.y, v.z, v.w};
    #pragma unroll
    for (int j = 0; j < 4; ++j) {
        __bf16 hh = (__bf16)x[j];
        h[j] = hh;
        l[j] = (__bf16)(x[j] - (float)hh);
    }
}

__global__ __launch_bounds__(256) void gram_hilo_kernel(
        const float* __restrict__ feats,
        float* __restrict__ gram) {
    __shared__ __bf16 Ah[2][64][PLW], Al[2][64][PLW];
    __shared__ __bf16 Bh[2][64][PLW], Bl[2][64][PLW];

    int pi = blockIdx.x;
    int by = c_by[pi], bx = c_bx[pi];
    int p0 = by * 64, q0 = bx * 64;
    int kbase = blockIdx.y * KPB;

    int tid = threadIdx.x;
    int lane = tid & 63;
    int w = tid >> 6;
    int wr = w >> 1, wc = w & 1;

    int r0 = tid >> 3;
    int slot = tid & 7;
    const float* ap0 = feats + (size_t)(p0 + r0)      * KTOT + kbase + slot * 4;
    const float* ap1 = feats + (size_t)(p0 + r0 + 32) * KTOT + kbase + slot * 4;
    const float* bp0 = feats + (size_t)(q0 + r0)      * KTOT + kbase + slot * 4;
    const float* bp1 = feats + (size_t)(q0 + r0 + 32) * KTOT + kbase + slot * 4;

    int frow = lane & 31;
    int arow = 32 * wr + frow;
    int brow = 32 * wc + frow;
    int kq = (lane >> 5) * 8;

    floatx16 acc = {};

    {
        float4 a0 = *(const float4*)ap0;
        float4 a1 = *(const float4*)ap1;
        float4 b0 = *(const float4*)bp0;
        float4 b1 = *(const float4*)bp1;
        bf16x4 h, l;
        split4(a0, h, l); *(bf16x4*)&Ah[0][r0][slot*4] = h;      *(bf16x4*)&Al[0][r0][slot*4] = l;
        split4(a1, h, l); *(bf16x4*)&Ah[0][r0+32][slot*4] = h;   *(bf16x4*)&Al[0][r0+32][slot*4] = l;
        split4(b0, h, l); *(bf16x4*)&Bh[0][r0][slot*4] = h;      *(bf16x4*)&Bl[0][r0][slot*4] = l;
        split4(b1, h, l); *(bf16x4*)&Bh[0][r0+32][slot*4] = h;   *(bf16x4*)&Bl[0][r0+32][slot*4] = l;
    }
    __syncthreads();

    for (int s = 0; s < GNB; ++s) {
        int buf = s & 1;
        float4 a0, a1, b0, b1;
        if (s + 1 < GNB) {
            int off = (s + 1) * GBK;
            a0 = *(const float4*)(ap0 + off);
            a1 = *(const float4*)(ap1 + off);
            b0 = *(const float4*)(bp0 + off);
            b1 = *(const float4*)(bp1 + off);
        }
        #pragma unroll
        for (int kk = 0; kk < 2; ++kk) {
            int ko = kq + kk * 16;
            bf16x8 ah = *(const bf16x8*)&Ah[buf][arow][ko];
            bf16x8 al = *(const bf16x8*)&Al[buf][arow][ko];
            bf16x8 bh = *(const bf16x8*)&Bh[buf][brow][ko];
            bf16x8 bl = *(const bf16x8*)&Bl[buf][brow][ko];
            acc = __builtin_amdgcn_mfma_f32_32x32x16_bf16(ah, bh, acc, 0, 0, 0);
            acc = __builtin_amdgcn_mfma_f32_32x32x16_bf16(ah, bl, acc, 0, 0, 0);
            acc = __builtin_amdgcn_mfma_f32_32x32x16_bf16(al, bh, acc, 0, 0, 0);
        }
        if (s + 1 < GNB) {
            int nb = (s + 1) & 1;
            bf16x4 h, l;
            split4(a0, h, l); *(bf16x4*)&Ah[nb][r0][slot*4] = h;      *(bf16x4*)&Al[nb][r0][slot*4] = l;
            split4(a1, h, l); *(bf16x4*)&Ah[nb][r0+32][slot*4] = h;   *(bf16x4*)&Al[nb][r0+32][slot*4] = l;
            split4(b0, h, l); *(bf16x4*)&Bh[nb][r0][slot*4] = h;      *(bf16x4*)&Bl[nb][r0][slot*4] = l;
            split4(b1, h, l); *(bf16x4*)&Bh[nb][r0+32][slot*4] = h;   *(bf16x4*)&Bl[nb][r0+32][slot*4] = l;
        }
        __syncthreads();
    }

    const float scale = 1.0f / 14680064.0f;
    int col = lane & 31;
    #pragma unroll
    for (int r = 0; r < 16; ++r) {
        int row = (r & 3) + 8 * (r >> 2) + 4 * (lane >> 5);
        int p = p0 + 32 * wr + row;
        int q = q0 + 32 * wc + col;
        float v = acc[r] * scale;
        atomicAdd(&gram[(size_t)p * GD + q], v);
        if (bx != by) atomicAdd(&gram[(size_t)q * GD + p], v);
    }
}

// ---------------------------------------------------------------- launch
extern "C" void kernel_launch(void* const* d_in, const int* in_sizes, int n_in,
                              void* d_out, int out_size, void* d_ws, size_t ws_size,
                              hipStream_t stream) {
    const float* img   = (const float*)d_in[0];
    const float* pupil = (const float*)d_in[1];
    const float* iris  = (const float*)d_in[2];
    const float* fm    = (const float*)d_in[3];

    float* codes = (float*)d_out;
    float* gram  = codes + CODES_N;
    float* polar = gram + GRAM_N;

    bool use_bf = (ws_size >= BF_BYTES);
    __bf16* cbf = use_bf ? (__bf16*)d_ws : nullptr;

    hipMemsetAsync(gram, 0, GRAM_N * sizeof(float), stream);

    polar_kernel<<<(int)(POLAR_N / 256), 256, 0, stream>>>(img, pupil, iris, polar);

    conv_kernel<<<BB * (PH / 4), 256, 0, stream>>>(polar, fm, codes, cbf);

    dim3 ggrid(28, SPLITS);
    if (use_bf)
        gram_bf_kernel<<<ggrid, 256, 0, stream>>>((const __bf16*)d_ws, gram);
    else
        gram_hilo_kernel<<<ggrid, 256, 0, stream>>>(codes, gram);
}

// Round 6
// 234.567 us; speedup vs baseline: 2.0615x; 1.4068x over previous
//
#include <hip/hip_runtime.h>
#include <math.h>

#define BB 64
#define HH 480
#define WW 640
#define PH 64
#define PW 512
#define FS 15
#define NF 7
#define RR 7              // FS/2
#define GD 448            // B*NF
#define KTOT 32768        // PH*PW

#define GSPL 16               // gram K splits (partial planes in ws)
#define KPB (KTOT / GSPL)     // 2048 K per block
#define GSTK 64               // K per LDS stage
#define GNST (KPB / GSTK)     // 32 stages
#define GPLW 72               // padded LDS row width (bf16 elems)

// fallback (hi/lo, atomic) gram params
#define FSPL 32
#define FKPB (KTOT / FSPL)
#define GBK 32
#define GNB (FKPB / GBK)
#define PLW 40

#define SRW 536               // conv sRow padded width

static constexpr long CODES_N = (long)BB * NF * PH * PW;   // 14,680,064
static constexpr long GRAM_N  = (long)GD * GD;             // 200,704
static constexpr long POLAR_N = (long)BB * PH * PW;        // 2,097,152
static constexpr size_t BF_BYTES   = (size_t)GD * KTOT * 2;        // 28 MB
static constexpr size_t PART_BYTES = (size_t)GSPL * GRAM_N * 4;    // 12.8 MB

typedef __bf16  bf16x4   __attribute__((ext_vector_type(4)));
typedef __bf16  bf16x8   __attribute__((ext_vector_type(8)));
typedef float   floatx16 __attribute__((ext_vector_type(16)));

// upper-triangle 64x64 tile pairs (by<=bx), 7 tiles -> 28 pairs
__constant__ int c_by[28] = {0,0,0,0,0,0,0, 1,1,1,1,1,1, 2,2,2,2,2, 3,3,3,3, 4,4,4, 5,5, 6};
__constant__ int c_bx[28] = {0,1,2,3,4,5,6, 1,2,3,4,5,6, 2,3,4,5,6, 3,4,5,6, 4,5,6, 5,6, 6};

// ---------------------------------------------------------------- K1: polar unwarp
__global__ __launch_bounds__(256) void polar_kernel(
        const float* __restrict__ img,
        const float* __restrict__ pupil,
        const float* __restrict__ iris,
        float* __restrict__ polar) {
    int t = blockIdx.x * 256 + threadIdx.x;
    if (t >= (int)POLAR_N) return;
    int j = t & (PW - 1);
    int i = (t >> 9) & (PH - 1);
    int b = t >> 15;

    float theta = 6.2831855f * (float)(j + 1) / (float)PW;
    float s, c;
    __sincosf(theta, &s, &c);

    float pcx = pupil[b * 3 + 0], pcy = pupil[b * 3 + 1], pr = pupil[b * 3 + 2];
    float icx = iris[b * 3 + 0],  icy = iris[b * 3 + 1],  ir = iris[b * 3 + 2];

    float px = pcx + pr * c;
    float py = pcy + pr * s;
    float ix = icx + ir * c;
    float iy = icy + ir * s;

    float r = (float)i / 63.0f;
    float xg = (1.0f - r) * px + r * ix;
    float yg = (1.0f - r) * py + r * iy;

    float x = fminf(fmaxf(xg, 0.0f), (float)(WW - 1));
    float y = fminf(fmaxf(yg, 0.0f), (float)(HH - 1));

    float xn = x / (float)(WW - 1) * 2.0f - 1.0f;
    float gx = ((xn + 1.0f) / 2.0f * (float)WW - 0.5f) / (float)(WW - 1) * 2.0f - 1.0f;
    float xs = ((gx + 1.0f) * (float)WW - 1.0f) / 2.0f;

    float yn = y / (float)(HH - 1) * 2.0f - 1.0f;
    float gy = ((yn + 1.0f) / 2.0f * (float)HH - 0.5f) / (float)(HH - 1) * 2.0f - 1.0f;
    float ys = ((gy + 1.0f) * (float)HH - 1.0f) / 2.0f;

    float x0f = floorf(xs), y0f = floorf(ys);
    float wx = xs - x0f, wy = ys - y0f;
    int x0 = (int)x0f, y0 = (int)y0f;

    const float* im = img + (size_t)b * (HH * WW);
    float v00 = 0.f, v01 = 0.f, v10 = 0.f, v11 = 0.f;
    bool xv0 = (x0 >= 0) & (x0 < WW);
    bool xv1 = (x0 + 1 >= 0) & (x0 + 1 < WW);
    bool yv0 = (y0 >= 0) & (y0 < HH);
    bool yv1 = (y0 + 1 >= 0) & (y0 + 1 < HH);
    if (xv0 & yv0) v00 = im[(size_t)y0 * WW + x0];
    if (xv1 & yv0) v01 = im[(size_t)y0 * WW + x0 + 1];
    if (xv0 & yv1) v10 = im[(size_t)(y0 + 1) * WW + x0];
    if (xv1 & yv1) v11 = im[(size_t)(y0 + 1) * WW + x0 + 1];

    float val = v00 * (1.0f - wx) * (1.0f - wy) + v01 * wx * (1.0f - wy)
              + v10 * (1.0f - wx) * wy          + v11 * wx * wy;
    polar[t] = val * 255.0f;
}

// ---------------------------------------------------------------- K2: wrap conv 15x15x7
// block = (b, 4 output rows); 4 waves; thread: 8 j x 7 o.
// Weights read straight from global (wave-uniform -> scalar loads).
__global__ __launch_bounds__(256) void conv_kernel(
        const float* __restrict__ polar,
        const float* __restrict__ fm,
        float* __restrict__ codes,
        __bf16* __restrict__ cbf) {
    __shared__ float sRow[18][SRW];        // rows i0-7 .. i0+10, wrap-padded cols

    int b  = blockIdx.x >> 4;
    int i0 = (blockIdx.x & 15) * 4;
    int tid = threadIdx.x;

    const float* pb = polar + (size_t)b * (PH * PW);

    #pragma unroll
    for (int pass = 0; pass < 9; ++pass) {
        int r = pass * 2 + (tid >> 7);
        int c = tid & 127;
        int row = (i0 + r - RR) & (PH - 1);
        float4 v = *(const float4*)&pb[(size_t)row * PW + c * 4];
        *(float4*)&sRow[r][RR + c * 4] = v;
    }
    if (tid < 252) {
        int r = tid / 14, l = tid % 14;
        int row = (i0 + r - RR) & (PH - 1);
        const float* prow = pb + (size_t)row * PW;
        if (l < RR) sRow[r][l] = prow[505 + l];
        else        sRow[r][512 + l] = prow[l - RR];
    }
    __syncthreads();

    int w = tid >> 6;
    int lane = tid & 63;
    int jb = lane * 8;
    int i = i0 + w;

    float acc[8][NF];
    #pragma unroll
    for (int jo = 0; jo < 8; ++jo)
        #pragma unroll
        for (int o = 0; o < NF; ++o) acc[jo][o] = 0.0f;

    for (int u = 0; u < FS; ++u) {
        float4 w4[6];
        #pragma unroll
        for (int l = 0; l < 6; ++l)
            w4[l] = *(const float4*)&sRow[w + u][jb + 4 * l];
        float win[24];
        #pragma unroll
        for (int l = 0; l < 6; ++l) {
            win[4*l+0] = w4[l].x; win[4*l+1] = w4[l].y;
            win[4*l+2] = w4[l].z; win[4*l+3] = w4[l].w;
        }
        #pragma unroll
        for (int v = 0; v < FS; ++v) {
            float wv[NF];
            #pragma unroll
            for (int o = 0; o < NF; ++o)
                wv[o] = fm[(u * FS + v) * NF + (NF - 1 - o)];   // uniform -> s_load
            #pragma unroll
            for (int jo = 0; jo < 8; ++jo) {
                float x = win[jo + v];
                #pragma unroll
                for (int o = 0; o < NF; ++o)
                    acc[jo][o] = fmaf(x, wv[o], acc[jo][o]);
            }
        }
    }

    #pragma unroll
    for (int o = 0; o < NF; ++o) {
        size_t base = (((size_t)b * NF + o) * PH + i) * PW + jb;
        *(float4*)&codes[base]     = make_float4(acc[0][o], acc[1][o], acc[2][o], acc[3][o]);
        *(float4*)&codes[base + 4] = make_float4(acc[4][o], acc[5][o], acc[6][o], acc[7][o]);
    }
    if (cbf) {
        #pragma unroll
        for (int o = 0; o < NF; ++o) {
            bf16x8 bv;
            #pragma unroll
            for (int jo = 0; jo < 8; ++jo) bv[jo] = (__bf16)acc[jo][o];
            *(bf16x8*)&cbf[(((size_t)b * NF + o) * PH + i) * PW + jb] = bv;
        }
    }
}

// ---------------------------------------------------------------- K3: gram, bf16 MFMA SYRK -> partial planes (no atomics)
__global__ __launch_bounds__(256) void gram_bf_kernel(
        const __bf16* __restrict__ feats,
        float* __restrict__ partials) {
    __shared__ __bf16 Ab[2][64][GPLW];
    __shared__ __bf16 Bb[2][64][GPLW];

    int pi = blockIdx.x;
    int by = c_by[pi], bx = c_bx[pi];
    int p0 = by * 64, q0 = bx * 64;
    size_t kbase = (size_t)blockIdx.y * KPB;

    int tid = threadIdx.x;
    int lane = tid & 63;
    int w = tid >> 6;
    int wr = w >> 1, wc = w & 1;        // 2x2 waves over 64x64 tile

    int srow = tid >> 3;                // 0..31
    int slot = tid & 7;                 // k-octet
    const __bf16* apA  = feats + (size_t)(p0 + srow) * KTOT + kbase + slot * 8;
    const __bf16* apA2 = apA + (size_t)32 * KTOT;
    const __bf16* apB  = feats + (size_t)(q0 + srow) * KTOT + kbase + slot * 8;
    const __bf16* apB2 = apB + (size_t)32 * KTOT;

    int arow = 32 * wr + (lane & 31);
    int brow = 32 * wc + (lane & 31);
    int ko = (lane >> 5) * 8;

    floatx16 acc = {};

    bf16x8 ra0 = *(const bf16x8*)(apA);
    bf16x8 ra1 = *(const bf16x8*)(apA2);
    bf16x8 rb0 = *(const bf16x8*)(apB);
    bf16x8 rb1 = *(const bf16x8*)(apB2);
    bf16x8 na0 = *(const bf16x8*)(apA + GSTK);
    bf16x8 na1 = *(const bf16x8*)(apA2 + GSTK);
    bf16x8 nb0 = *(const bf16x8*)(apB + GSTK);
    bf16x8 nb1 = *(const bf16x8*)(apB2 + GSTK);

    for (int s = 0; s < GNST; ++s) {
        int p = s & 1;
        *(bf16x8*)&Ab[p][srow][slot * 8]      = ra0;
        *(bf16x8*)&Ab[p][srow + 32][slot * 8] = ra1;
        *(bf16x8*)&Bb[p][srow][slot * 8]      = rb0;
        *(bf16x8*)&Bb[p][srow + 32][slot * 8] = rb1;
        __syncthreads();
        ra0 = na0; ra1 = na1; rb0 = nb0; rb1 = nb1;
        if (s + 2 < GNST) {
            size_t off = (size_t)(s + 2) * GSTK;
            na0 = *(const bf16x8*)(apA + off);
            na1 = *(const bf16x8*)(apA2 + off);
            nb0 = *(const bf16x8*)(apB + off);
            nb1 = *(const bf16x8*)(apB2 + off);
        }
        #pragma unroll
        for (int st = 0; st < 4; ++st) {
            bf16x8 af = *(const bf16x8*)&Ab[p][arow][st * 16 + ko];
            bf16x8 bg = *(const bf16x8*)&Bb[p][brow][st * 16 + ko];
            acc = __builtin_amdgcn_mfma_f32_32x32x16_bf16(af, bg, acc, 0, 0, 0);
        }
    }

    float* part = partials + (size_t)blockIdx.y * GRAM_N;
    int col = lane & 31;
    #pragma unroll
    for (int r = 0; r < 16; ++r) {
        int row = (r & 3) + 8 * (r >> 2) + 4 * (lane >> 5);
        int p = p0 + 32 * wr + row;
        int q = q0 + 32 * wc + col;
        float v = acc[r];
        part[(size_t)p * GD + q] = v;
        if (bx != by) part[(size_t)q * GD + p] = v;
    }
}

// ---------------------------------------------------------------- K4: reduce partials -> gram
__global__ __launch_bounds__(256) void gram_reduce_kernel(
        const float* __restrict__ partials,
        float* __restrict__ gram) {
    int t = blockIdx.x * 256 + threadIdx.x;   // 50176 float4 groups
    const float scale = 1.0f / 14680064.0f;
    float4 s = make_float4(0.f, 0.f, 0.f, 0.f);
    #pragma unroll
    for (int sp = 0; sp < GSPL; ++sp) {
        float4 v = *(const float4*)&partials[(size_t)sp * GRAM_N + (size_t)t * 4];
        s.x += v.x; s.y += v.y; s.z += v.z; s.w += v.w;
    }
    s.x *= scale; s.y *= scale; s.z *= scale; s.w *= scale;
    *(float4*)&gram[(size_t)t * 4] = s;
}

// ---------------------------------------------------------------- K3 fallback: hi/lo split, atomics (no ws needed)
__device__ __forceinline__ void split4(float4 v, bf16x4& h, bf16x4& l) {
    float x[4] = {v.x, v.y, v.z, v.w};
    #pragma unroll
    for (int j = 0; j < 4; ++j) {
        __bf16 hh = (__bf16)x[j];
        h[j] = hh;
        l[j] = (__bf16)(x[j] - (float)hh);
    }
}

__global__ __launch_bounds__(256) void gram_hilo_kernel(
        const float* __restrict__ feats,
        float* __restrict__ gram) {
    __shared__ __bf16 Ah[2][64][PLW], Al[2][64][PLW];
    __shared__ __bf16 Bh[2][64][PLW], Bl[2][64][PLW];

    int pi = blockIdx.x;
    int by = c_by[pi], bx = c_bx[pi];
    int p0 = by * 64, q0 = bx * 64;
    int kbase = blockIdx.y * FKPB;

    int tid = threadIdx.x;
    int lane = tid & 63;
    int w = tid >> 6;
    int wr = w >> 1, wc = w & 1;

    int r0 = tid >> 3;
    int slot = tid & 7;
    const float* ap0 = feats + (size_t)(p0 + r0)      * KTOT + kbase + slot * 4;
    const float* ap1 = feats + (size_t)(p0 + r0 + 32) * KTOT + kbase + slot * 4;
    const float* bp0 = feats + (size_t)(q0 + r0)      * KTOT + kbase + slot * 4;
    const float* bp1 = feats + (size_t)(q0 + r0 + 32) * KTOT + kbase + slot * 4;

    int frow = lane & 31;
    int arow = 32 * wr + frow;
    int brow = 32 * wc + frow;
    int kq = (lane >> 5) * 8;

    floatx16 acc = {};

    {
        float4 a0 = *(const float4*)ap0;
        float4 a1 = *(const float4*)ap1;
        float4 b0 = *(const float4*)bp0;
        float4 b1 = *(const float4*)bp1;
        bf16x4 h, l;
        split4(a0, h, l); *(bf16x4*)&Ah[0][r0][slot*4] = h;      *(bf16x4*)&Al[0][r0][slot*4] = l;
        split4(a1, h, l); *(bf16x4*)&Ah[0][r0+32][slot*4] = h;   *(bf16x4*)&Al[0][r0+32][slot*4] = l;
        split4(b0, h, l); *(bf16x4*)&Bh[0][r0][slot*4] = h;      *(bf16x4*)&Bl[0][r0][slot*4] = l;
        split4(b1, h, l); *(bf16x4*)&Bh[0][r0+32][slot*4] = h;   *(bf16x4*)&Bl[0][r0+32][slot*4] = l;
    }
    __syncthreads();

    for (int s = 0; s < GNB; ++s) {
        int buf = s & 1;
        float4 a0, a1, b0, b1;
        if (s + 1 < GNB) {
            int off = (s + 1) * GBK;
            a0 = *(const float4*)(ap0 + off);
            a1 = *(const float4*)(ap1 + off);
            b0 = *(const float4*)(bp0 + off);
            b1 = *(const float4*)(bp1 + off);
        }
        #pragma unroll
        for (int kk = 0; kk < 2; ++kk) {
            int ko = kq + kk * 16;
            bf16x8 ah = *(const bf16x8*)&Ah[buf][arow][ko];
            bf16x8 al = *(const bf16x8*)&Al[buf][arow][ko];
            bf16x8 bh = *(const bf16x8*)&Bh[buf][brow][ko];
            bf16x8 bl = *(const bf16x8*)&Bl[buf][brow][ko];
            acc = __builtin_amdgcn_mfma_f32_32x32x16_bf16(ah, bh, acc, 0, 0, 0);
            acc = __builtin_amdgcn_mfma_f32_32x32x16_bf16(ah, bl, acc, 0, 0, 0);
            acc = __builtin_amdgcn_mfma_f32_32x32x16_bf16(al, bh, acc, 0, 0, 0);
        }
        if (s + 1 < GNB) {
            int nb = (s + 1) & 1;
            bf16x4 h, l;
            split4(a0, h, l); *(bf16x4*)&Ah[nb][r0][slot*4] = h;      *(bf16x4*)&Al[nb][r0][slot*4] = l;
            split4(a1, h, l); *(bf16x4*)&Ah[nb][r0+32][slot*4] = h;   *(bf16x4*)&Al[nb][r0+32][slot*4] = l;
            split4(b0, h, l); *(bf16x4*)&Bh[nb][r0][slot*4] = h;      *(bf16x4*)&Bl[nb][r0][slot*4] = l;
            split4(b1, h, l); *(bf16x4*)&Bh[nb][r0+32][slot*4] = h;   *(bf16x4*)&Bl[nb][r0+32][slot*4] = l;
        }
        __syncthreads();
    }

    const float scale = 1.0f / 14680064.0f;
    int col = lane & 31;
    #pragma unroll
    for (int r = 0; r < 16; ++r) {
        int row = (r & 3) + 8 * (r >> 2) + 4 * (lane >> 5);
        int p = p0 + 32 * wr + row;
        int q = q0 + 32 * wc + col;
        float v = acc[r] * scale;
        atomicAdd(&gram[(size_t)p * GD + q], v);
        if (bx != by) atomicAdd(&gram[(size_t)q * GD + p], v);
    }
}

// ---------------------------------------------------------------- launch
extern "C" void kernel_launch(void* const* d_in, const int* in_sizes, int n_in,
                              void* d_out, int out_size, void* d_ws, size_t ws_size,
                              hipStream_t stream) {
    const float* img   = (const float*)d_in[0];
    const float* pupil = (const float*)d_in[1];
    const float* iris  = (const float*)d_in[2];
    const float* fm    = (const float*)d_in[3];

    float* codes = (float*)d_out;
    float* gram  = codes + CODES_N;
    float* polar = gram + GRAM_N;

    bool use_bf = (ws_size >= BF_BYTES + PART_BYTES);
    __bf16* cbf = use_bf ? (__bf16*)d_ws : nullptr;
    float* partials = (float*)((char*)d_ws + BF_BYTES);

    polar_kernel<<<(int)(POLAR_N / 256), 256, 0, stream>>>(img, pupil, iris, polar);

    conv_kernel<<<BB * (PH / 4), 256, 0, stream>>>(polar, fm, codes, cbf);

    if (use_bf) {
        dim3 ggrid(28, GSPL);
        gram_bf_kernel<<<ggrid, 256, 0, stream>>>((const __bf16*)d_ws, partials);
        gram_reduce_kernel<<<(int)(GRAM_N / 4 / 256), 256, 0, stream>>>(partials, gram);
    } else {
        hipMemsetAsync(gram, 0, GRAM_N * sizeof(float), stream);
        dim3 ggrid(28, FSPL);
        gram_hilo_kernel<<<ggrid, 256, 0, stream>>>(codes, gram);
    }
}